// Round 1
// baseline (326.363 us; speedup 1.0000x reference)
//
#include <hip/hip_runtime.h>

#define EPS 1e-5f
#define NTHR 256
#define NBLK 1024
#define NSLOT 8

typedef __bf16 bf16x8 __attribute__((ext_vector_type(8)));
typedef float f32x16 __attribute__((ext_vector_type(16)));

// d_ws layout:
//   [0, N*16*2)              bf16 copy of x, tile-major in MFMA B-frag order:
//                            xb[(t*64 + lane)*8 .. +8) = 8 bf16 for (tile t, lane)
//   [N*16*2, +3*NSLOT*64*4)  stats slots: layer L: stats[L*NSLOT*64 + slot*64 + idx]
//                            idx 0..31 = sum(z_L), 32..63 = sum(z_L^2)
//
// Layout algebra (m74/m101-verified 32x32x16 mappings):
//   C/D: col=lane&31 (data row), row p = (reg&3)+8*(reg>>2)+4h, h=lane>>5
//   A:   m=lane&31, k=8h+j ;  B: n=lane&31, k=8h+j
// Acc regs 0..7 / 8..15 feed the next layer's B-frag; next weights use columns
// permuted by phi(K)=(j&3)+8*(j>>2)+4h+16*kh (involution). BN scale a>0 folds
// into next-layer weight columns; shift e folds into the MFMA accumulator init.
//
// R1 change: batch-issued load pipeline. Old loop had only 2x16B loads in
// flight per wave -> Little's law caps BW at ~0.5 TB/s (latency-bound, all 4
// passes ~78us). Now DEPTH>=2 issues 8 tile loads before any compute
// (8KB/wave in flight), DEPTH==1 issues 4 tiles of fp32 (same 8KB/wave).

template<int DEPTH>
__global__ __launch_bounds__(NTHR) void k_fwd(
    const float* __restrict__ x, __bf16* __restrict__ xb,
    const float* __restrict__ W1, const float* __restrict__ b1,
    const float* __restrict__ g1, const float* __restrict__ be1,
    const float* __restrict__ W2, const float* __restrict__ b2,
    const float* __restrict__ g2, const float* __restrict__ be2,
    const float* __restrict__ W3, const float* __restrict__ b3,
    const float* __restrict__ g3, const float* __restrict__ be3,
    const float* __restrict__ W4, const float* __restrict__ b4,
    float* __restrict__ stats, float* __restrict__ out, int N)
{
    constexpr bool STATS = (DEPTH < 4);
    __shared__ float s_stat[3][64];
    __shared__ float s_a[3][32];
    __shared__ float s_e[3][32];
    __shared__ float s_b[64];

    const int tid = threadIdx.x;
    const float invN = 1.0f / (float)N;

    // Phase A: combine slot partials for layers whose stats are known
    if (tid < 64) {
        for (int L = 0; L < DEPTH - 1; ++L) {
            float a = 0.f;
            #pragma unroll
            for (int s = 0; s < NSLOT; ++s) a += stats[L * (NSLOT * 64) + s * 64 + tid];
            s_stat[L][tid] = a;
        }
    }
    __syncthreads();
    // Phase B: derive BN scale a and additive fold e per feature
    if (tid < 32) {
        const float* gs[3]  = {g1, g2, g3};
        const float* bes[3] = {be1, be2, be3};
        const float* bs[3]  = {b1, b2, b3};
        for (int L = 0; L < DEPTH - 1; ++L) {
            float mu = s_stat[L][tid] * invN;
            float v  = s_stat[L][32 + tid] * invN - mu * mu;
            float a  = gs[L][tid] * rsqrtf(v + EPS);
            s_a[L][tid] = a;
            s_e[L][tid] = bs[L][tid] - mu + bes[L][tid] / a;
        }
    }
    if (STATS && tid < 64) s_b[tid] = 0.f;
    __syncthreads();

    // Phase C: per-thread fragments and constants
    const int lane = tid & 63;
    const int h = lane >> 5;
    const int ml = lane & 31;

    bf16x8 w1f;
    {
        const float* p = W1 + ml * 16 + h * 8;
        #pragma unroll
        for (int j = 0; j < 8; ++j) w1f[j] = (__bf16)p[j];
    }
    bf16x8 w2f0 = {}, w2f1 = {}, w3f0 = {}, w3f1 = {};
    if (DEPTH >= 2) {
        #pragma unroll
        for (int kh = 0; kh < 2; ++kh)
            #pragma unroll
            for (int j = 0; j < 8; ++j) {
                int pk = (j & 3) + 8 * (j >> 2) + 4 * h + 16 * kh;
                float v = W2[ml * 32 + pk] * s_a[0][pk];
                if (kh == 0) w2f0[j] = (__bf16)v; else w2f1[j] = (__bf16)v;
            }
    }
    if (DEPTH >= 3) {
        #pragma unroll
        for (int kh = 0; kh < 2; ++kh)
            #pragma unroll
            for (int j = 0; j < 8; ++j) {
                int pk = (j & 3) + 8 * (j >> 2) + 4 * h + 16 * kh;
                float v = W3[ml * 32 + pk] * s_a[1][pk];
                if (kh == 0) w3f0[j] = (__bf16)v; else w3f1[j] = (__bf16)v;
            }
    }

    f32x16 c1, c2 = {}, c3 = {};
    float w4c[16];
    #pragma unroll
    for (int i = 0; i < 16; ++i) {
        int p = (i & 3) + 8 * (i >> 2) + 4 * h;
        c1[i] = (DEPTH == 1) ? b1[p] : s_e[0][p];
        if (DEPTH >= 2) c2[i] = (DEPTH == 2) ? b2[p] : s_e[1][p];
        if (DEPTH >= 3) c3[i] = (DEPTH == 3) ? b3[p] : s_e[2][p];
        if (DEPTH == 4) w4c[i] = W4[p] * s_a[2][p]; else w4c[i] = 0.f;
    }
    const float b4v = (DEPTH == 4) ? b4[0] : 0.f;

    const int ntiles = N >> 5;
    const int nwaves = gridDim.x * (NTHR / 64);
    const int gwave  = blockIdx.x * (NTHR / 64) + (tid >> 6);

    float sums[16], sqs[16];
    #pragma unroll
    for (int i = 0; i < 16; ++i) { sums[i] = 0.f; sqs[i] = 0.f; }

    auto tile = [&](int t, bf16x8 xf) {
        f32x16 a1 = __builtin_amdgcn_mfma_f32_32x32x16_bf16(w1f, xf, c1, 0, 0, 0);
        if (DEPTH == 1) {
            #pragma unroll
            for (int i = 0; i < 16; ++i) { sums[i] += a1[i]; sqs[i] = fmaf(a1[i], a1[i], sqs[i]); }
            return;
        }
        bf16x8 qa, qb;
        #pragma unroll
        for (int j = 0; j < 8; ++j) {
            qa[j] = (__bf16)fmaxf(a1[j], 0.f);
            qb[j] = (__bf16)fmaxf(a1[8 + j], 0.f);
        }
        f32x16 a2 = __builtin_amdgcn_mfma_f32_32x32x16_bf16(w2f0, qa, c2, 0, 0, 0);
        a2 = __builtin_amdgcn_mfma_f32_32x32x16_bf16(w2f1, qb, a2, 0, 0, 0);
        if (DEPTH == 2) {
            #pragma unroll
            for (int i = 0; i < 16; ++i) { sums[i] += a2[i]; sqs[i] = fmaf(a2[i], a2[i], sqs[i]); }
            return;
        }
        bf16x8 pa, pb;
        #pragma unroll
        for (int j = 0; j < 8; ++j) {
            pa[j] = (__bf16)fmaxf(a2[j], 0.f);
            pb[j] = (__bf16)fmaxf(a2[8 + j], 0.f);
        }
        f32x16 a3 = __builtin_amdgcn_mfma_f32_32x32x16_bf16(w3f0, pa, c3, 0, 0, 0);
        a3 = __builtin_amdgcn_mfma_f32_32x32x16_bf16(w3f1, pb, a3, 0, 0, 0);
        if (DEPTH == 3) {
            #pragma unroll
            for (int i = 0; i < 16; ++i) { sums[i] += a3[i]; sqs[i] = fmaf(a3[i], a3[i], sqs[i]); }
            return;
        }
        float o = 0.f;
        #pragma unroll
        for (int i = 0; i < 16; ++i) o = fmaf(w4c[i], fmaxf(a3[i], 0.f), o);
        o += __shfl_xor(o, 32);
        if (h == 0) out[(t << 5) + ml] = o + b4v;
    };

    if (DEPTH == 1) {
        // 4-deep pipeline: issue 4 tiles' fp32 loads (8KB/wave in flight),
        // then convert + stage + compute.
        for (int t0 = gwave; t0 < ntiles; t0 += 4 * nwaves) {
            float4 u0[4], u1[4];
            #pragma unroll
            for (int k = 0; k < 4; ++k) {
                int t = t0 + k * nwaves;
                if (t < ntiles) {
                    int row = (t << 5) + ml;
                    const float4* xp = (const float4*)(x + (size_t)row * 16 + h * 8);
                    u0[k] = xp[0]; u1[k] = xp[1];
                }
            }
            #pragma unroll
            for (int k = 0; k < 4; ++k) {
                int t = t0 + k * nwaves;
                if (t < ntiles) {
                    bf16x8 xf;
                    xf[0] = (__bf16)u0[k].x; xf[1] = (__bf16)u0[k].y;
                    xf[2] = (__bf16)u0[k].z; xf[3] = (__bf16)u0[k].w;
                    xf[4] = (__bf16)u1[k].x; xf[5] = (__bf16)u1[k].y;
                    xf[6] = (__bf16)u1[k].z; xf[7] = (__bf16)u1[k].w;
                    *(bf16x8*)(xb + ((size_t)t * 64 + lane) * 8) = xf;
                    tile(t, xf);
                }
            }
        }
    } else {
        // 8-deep pipeline: issue 8 bf16 tile loads before any compute.
        for (int t0 = gwave; t0 < ntiles; t0 += 8 * nwaves) {
            bf16x8 xf[8];
            #pragma unroll
            for (int k = 0; k < 8; ++k) {
                int t = t0 + k * nwaves;
                if (t < ntiles) xf[k] = *(const bf16x8*)(xb + ((size_t)t * 64 + lane) * 8);
            }
            #pragma unroll
            for (int k = 0; k < 8; ++k) {
                int t = t0 + k * nwaves;
                if (t < ntiles) tile(t, xf[k]);
            }
        }
    }

    if (STATS) {
        #pragma unroll
        for (int i = 0; i < 16; ++i) {
            float s = sums[i], q = sqs[i];
            #pragma unroll
            for (int d = 1; d <= 16; d <<= 1) {
                s += __shfl_xor(s, d);
                q += __shfl_xor(q, d);
            }
            if (ml == 0) {
                int p = (i & 3) + 8 * (i >> 2) + 4 * h;
                atomicAdd(&s_b[p], s);
                atomicAdd(&s_b[32 + p], q);
            }
        }
        __syncthreads();
        if (tid < 64) {
            int L = DEPTH - 1;
            atomicAdd(&stats[L * (NSLOT * 64) + (blockIdx.x & (NSLOT - 1)) * 64 + tid], s_b[tid]);
        }
    }
}

extern "C" void kernel_launch(void* const* d_in, const int* in_sizes, int n_in,
                              void* d_out, int out_size, void* d_ws, size_t ws_size,
                              hipStream_t stream) {
    const float* x   = (const float*)d_in[0];
    const float* W1  = (const float*)d_in[1];
    const float* b1  = (const float*)d_in[2];
    const float* g1  = (const float*)d_in[3];
    const float* be1 = (const float*)d_in[4];
    const float* W2  = (const float*)d_in[5];
    const float* b2  = (const float*)d_in[6];
    const float* g2  = (const float*)d_in[7];
    const float* be2 = (const float*)d_in[8];
    const float* W3  = (const float*)d_in[9];
    const float* b3  = (const float*)d_in[10];
    const float* g3  = (const float*)d_in[11];
    const float* be3 = (const float*)d_in[12];
    const float* W4  = (const float*)d_in[13];
    const float* b4  = (const float*)d_in[14];
    float* out = (float*)d_out;
    int N = in_sizes[0] / 16;

    __bf16* xb   = (__bf16*)d_ws;
    float* stats = (float*)((char*)d_ws + (size_t)N * 16 * 2);

    hipMemsetAsync(stats, 0, 3 * NSLOT * 64 * sizeof(float), stream);

    k_fwd<1><<<NBLK, NTHR, 0, stream>>>(x, xb, W1, b1, g1, be1, W2, b2, g2, be2, W3, b3, g3, be3, W4, b4, stats, out, N);
    k_fwd<2><<<NBLK, NTHR, 0, stream>>>(x, xb, W1, b1, g1, be1, W2, b2, g2, be2, W3, b3, g3, be3, W4, b4, stats, out, N);
    k_fwd<3><<<NBLK, NTHR, 0, stream>>>(x, xb, W1, b1, g1, be1, W2, b2, g2, be2, W3, b3, g3, be3, W4, b4, stats, out, N);
    k_fwd<4><<<NBLK, NTHR, 0, stream>>>(x, xb, W1, b1, g1, be1, W2, b2, g2, be2, W3, b3, g3, be3, W4, b4, stats, out, N);
}